// Round 16
// baseline (228.754 us; speedup 1.0000x reference)
//
#include <hip/hip_runtime.h>

// GRU-D: nf=64, B=128, T=100, I=64, H=128, C=256.
// R16 = R15 + lgkmcnt-only barriers in the main loop (no vmcnt(0) drain):
//       input prefetch loads stay in flight across barriers (T4 pattern).
#define NF 64
#define BATCH 128
#define TT 100
#define II 64
#define HH 128
#define CC 256
#define BB 32
#define NTHR 512
#define PSTRIDE 111297

#define OFF_ZW 0
#define OFF_ZB 32768
#define OFF_RW 32896
#define OFF_RB 65664
#define OFF_HW 65792
#define OFF_HB 98560
#define OFF_GXW 98688
#define OFF_GXB 102784
#define OFF_GHW 102848
#define OFF_GHB 111040
#define OFF_FCW 111168
#define OFF_FCB 111296

#define LOG2E 1.4426950408889634f

// ws layout (bf16 elems), per-lane MFMA B-fragment order (hi only, pre-scaled)
#define ZR_PER_N 65536
#define H_BASE   (64 * ZR_PER_N)
#define H_PER_N  32768
#define G_BASE   (H_BASE + 64 * H_PER_N)
#define G_PER_N  8192
#define WS_ELEMS (G_BASE + 64 * G_PER_N)   // 6815744 bf16 = 13 MB

typedef __bf16 bf16x8 __attribute__((ext_vector_type(8)));
typedef __bf16 bf16x4 __attribute__((ext_vector_type(4)));
typedef float f32x4 __attribute__((ext_vector_type(4)));

__device__ __forceinline__ f32x4 mfma16(bf16x8 a, bf16x8 b, f32x4 c) {
  return __builtin_amdgcn_mfma_f32_16x16x32_bf16(a, b, c, 0, 0, 0);
}
__device__ __forceinline__ float rcpf_(float x) { return __builtin_amdgcn_rcpf(x); }
__device__ __forceinline__ float exp2_(float x) { return __builtin_amdgcn_exp2f(x); }
// inputs already scaled by log2e:
__device__ __forceinline__ float sig2_(float x) { return rcpf_(1.f + exp2_(-x)); }
// input already scaled by 2*log2e:
__device__ __forceinline__ float tanh2_(float x) {
  return fmaf(2.f, rcpf_(1.f + exp2_(-x)), -1.f);
}
// barrier that waits ONLY on LDS ops (keeps global prefetch in flight)
__device__ __forceinline__ void barrier_lgkm() {
  asm volatile("s_waitcnt lgkmcnt(0)\n\ts_barrier" ::: "memory");
}
// row swizzle within a [64][8] plane: physical row = r ^ 2*((r>>4)&3)
__device__ __forceinline__ int SW(int x) { return x ^ (((x >> 4) & 3) << 1); }

// LDS pool element-offsets (plane = [64 rows][8 j] = 512 elems):
#define XA(par, mt, kt)  ((((par)*2 + (mt)) * 2 + (kt)) * 512)
#define MAPL(par, mt, kt) (4096 + XA(par, mt, kt))
#define DAH(mt, kt) (8192 + (((mt)*2 + (kt)) * 512))
#define HAH(mt, q) (10240 + (((mt)*4 + (q)) * 512))
#define RHH(mt, q) (14336 + (((mt)*4 + (q)) * 512))
#define POOL_ELEMS 18432

// ---- repack: params -> B-fragment-ordered bf16 (hi only, log2e-scaled) ----
__global__ void repack_kernel(const float* __restrict__ p, __bf16* __restrict__ ws) {
  const int total = 4194304 + 2097152 + 524288;
  for (int e = blockIdx.x * 256 + threadIdx.x; e < total; e += gridDim.x * 256) {
    float wv; int dst;
    if (e < 4194304) {  // ZR  (scale log2e)
      int j = e & 7, l = (e >> 3) & 63, nt = (e >> 9) & 15, kt = (e >> 13) & 7, n = e >> 16;
      int c = kt * 32 + (l >> 4) * 8 + j, l15 = l & 15;
      long pn = (long)n * PSTRIDE;
      wv = (nt < 8) ? p[pn + OFF_ZW + (nt * 16 + l15) * CC + c]
                    : p[pn + OFF_RW + ((nt - 8) * 16 + l15) * CC + c];
      wv *= LOG2E;
      dst = n * ZR_PER_N + (kt * 16 + nt) * 512 + l * 8 + j;
    } else if (e < 4194304 + 2097152) {  // H  (scale 2*log2e for tanh form)
      int e2 = e - 4194304;
      int j = e2 & 7, l = (e2 >> 3) & 63, nt = (e2 >> 9) & 7, kt = (e2 >> 12) & 7, n = e2 >> 15;
      int c = kt * 32 + (l >> 4) * 8 + j, l15 = l & 15;
      wv = p[(long)n * PSTRIDE + OFF_HW + (nt * 16 + l15) * CC + c] * (2.f * LOG2E);
      dst = H_BASE + n * H_PER_N + (kt * 8 + nt) * 512 + l * 8 + j;
    } else {  // G  (scale log2e)
      int e2 = e - (4194304 + 2097152);
      int j = e2 & 7, l = (e2 >> 3) & 63, nt = (e2 >> 9) & 7, kt = (e2 >> 12) & 1, n = e2 >> 13;
      int c = kt * 32 + (l >> 4) * 8 + j, l15 = l & 15;
      wv = p[(long)n * PSTRIDE + OFF_GHW + (nt * 16 + l15) * II + c] * LOG2E;
      dst = G_BASE + n * G_PER_N + (kt * 8 + nt) * 512 + l * 8 + j;
    }
    ws[dst] = (__bf16)wv;
  }
}

// One block per (n, 32-batch chunk); 8 waves; 1 block/CU.
__global__ __launch_bounds__(NTHR, 2) void grud_main(
    const float* __restrict__ p, const float* __restrict__ X,
    const float* __restrict__ XL, const float* __restrict__ XM,
    const float* __restrict__ MK, const float* __restrict__ DE,
    const __bf16* __restrict__ ws, float* __restrict__ out) {
  __shared__ __align__(16) __bf16 pool[POOL_ELEMS];

  const int tid = threadIdx.x;
  const int w = tid >> 6, l = tid & 63;
  const int l15 = l & 15, lg = l >> 4;
  const int n = blockIdx.x & 63;            // same-n blocks -> same XCD
  const int b0 = (blockIdx.x >> 6) * BB;
  const long pn = (long)n * PSTRIDE;
  const int cw = w * 16 + l15;
  const int sl = SW(l);

  // ---- all weight fragments in registers (loaded once, 104 VGPR) ----
  bf16x8 wgR[2], wzR[8], wrR[8], whR[8];
  {
    const __bf16* wzr = ws + n * ZR_PER_N;
    const __bf16* wh_ = ws + H_BASE + n * H_PER_N;
    const __bf16* wg_ = ws + G_BASE + n * G_PER_N;
#pragma unroll
    for (int kt = 0; kt < 2; ++kt)
      wgR[kt] = *(const bf16x8*)(wg_ + (kt * 8 + w) * 512 + l * 8);
#pragma unroll
    for (int kt = 0; kt < 8; ++kt) {
      wzR[kt] = *(const bf16x8*)(wzr + (kt * 16 + w) * 512 + l * 8);
      wrR[kt] = *(const bf16x8*)(wzr + (kt * 16 + 8 + w) * 512 + l * 8);
      whR[kt] = *(const bf16x8*)(wh_ + (kt * 8 + w) * 512 + l * 8);
    }
  }

  const float zb = p[pn + OFF_ZB + cw] * LOG2E;
  const float rb = p[pn + OFF_RB + cw] * LOG2E;
  const float hb = p[pn + OFF_HB + cw] * (2.f * LOG2E);
  const float gb = p[pn + OFF_GHB + cw] * LOG2E;
  const f32x4 zb4 = {zb, zb, zb, zb};
  const f32x4 rb4 = {rb, rb, rb, rb};
  const f32x4 hb4 = {hb, hb, hb, hb};
  const f32x4 gb4 = {gb, gb, gb, gb};

  // this lane's h-column coords (global k = 64 + cw)
  const int hq = ((64 + cw) >> 5) - 2;                 // plane q 0..3
  const int qh = (cw >> 3) & 3;
  const int hj = cw & 7;
  int hsrow[4];
#pragma unroll
  for (int r = 0; r < 4; ++r) hsrow[r] = qh * 16 + ((lg * 4 + r) ^ (qh << 1));

  // phase-A mapping: thread -> (batch row 0..31, 4-wide i block)
  const int arow = tid >> 4;
  const int ai0 = (tid & 15) * 4;
  const int amt = arow >> 4;
  const int akt = ai0 >> 5;
  const int salane = SW(((ai0 >> 3) & 3) * 16 + (arow & 15));
  const int aj = ai0 & 7;
  const float* __restrict__ Xp  = X  + (long)(b0 + arow) * TT * II + ai0;
  const float* __restrict__ XLp = XL + (long)(b0 + arow) * TT * II + ai0;
  const float* __restrict__ MKp = MK + ((long)(n * BATCH + b0 + arow) * TT) * II + ai0;
  const float* __restrict__ DEp = DE + ((long)(n * BATCH + b0 + arow) * TT) * II + ai0;
  float gxd4[4], gxb4v[4];
#pragma unroll
  for (int u = 0; u < 4; ++u) {
    gxd4[u] = p[pn + OFF_GXW + (ai0 + u) * 65] * LOG2E;
    gxb4v[u] = p[pn + OFF_GXB + ai0 + u] * LOG2E;
  }

  float h[2][4] = {{0.f, 0.f, 0.f, 0.f}, {0.f, 0.f, 0.f, 0.f}};
  f32x4 azp[2], arp[2];   // z,r partial accumulators (x/m part of step t)
  f32x4 ahp[2];           // h_tilde partial accumulator (x/m part of step t)
  f32x4 azs[2];           // completed z pre-activations, consumed in D

  // ---- prologue: zero hA planes; A(0); prefetch(1) ----
  for (int e = tid; e < 4096; e += NTHR) pool[10240 + e] = (__bf16)0.f;

  f32x4 fx  = *(const f32x4*)Xp;
  f32x4 fxl = *(const f32x4*)XLp;
  f32x4 fxm = *(const f32x4*)(XM + ai0);
  f32x4 fm  = __builtin_nontemporal_load((const f32x4*)MKp);
  f32x4 fd  = __builtin_nontemporal_load((const f32x4*)DEp);
  {
    bf16x4 xh, mh;
#pragma unroll
    for (int u = 0; u < 4; ++u) {
      float m = fm[u], d = fd[u];
      float dx = exp2_(-fmaxf(fmaf(d, gxd4[u], gxb4v[u]), 0.f));
      float b = fmaf(dx, fxl[u] - fxm[u], fxm[u]);
      float xv = fmaf(m, fx[u] - b, b);
      xh[u] = (__bf16)xv;
      mh[u] = (__bf16)m;
    }
    *(bf16x4*)&pool[XA(0, amt, akt) + salane * 8 + aj] = xh;
    *(bf16x4*)&pool[MAPL(0, amt, akt) + salane * 8 + aj] = mh;
  }
  {
    const long to = (long)(TT > 1 ? 1 : 0) * II;
    fx  = *(const f32x4*)(Xp + to);
    fxl = *(const f32x4*)(XLp + to);
    fxm = *(const f32x4*)(XM + to + ai0);
    fm  = __builtin_nontemporal_load((const f32x4*)(MKp + to));
    fd  = __builtin_nontemporal_load((const f32x4*)(DEp + to));
  }
  __syncthreads();

  // z,r x/m partials for t=0
#pragma unroll
  for (int mt = 0; mt < 2; ++mt) {
    f32x4 az = zb4, ar = rb4;
#pragma unroll
    for (int kt = 0; kt < 2; ++kt) {
      bf16x8 ah = *(const bf16x8*)&pool[XA(0, mt, kt) + sl * 8];
      az = mfma16(ah, wzR[kt], az);
      ar = mfma16(ah, wrR[kt], ar);
    }
#pragma unroll
    for (int kt = 6; kt < 8; ++kt) {
      bf16x8 ah = *(const bf16x8*)&pool[MAPL(0, mt, kt - 6) + sl * 8];
      az = mfma16(ah, wzR[kt], az);
      ar = mfma16(ah, wrR[kt], ar);
    }
    azp[mt] = az; arp[mt] = ar;
  }

  for (int t = 0; t < TT; ++t) {
    const int par = t & 1, parn = par ^ 1;
    const bool more = (t + 1 < TT);

    // ================= C-region =================
    // A(t+1): elementwise from prefetched regs -> parn planes + dA
    if (more) {
      bf16x4 xh, mh, dh;
#pragma unroll
      for (int u = 0; u < 4; ++u) {
        float m = fm[u], d = fd[u];
        float dx = exp2_(-fmaxf(fmaf(d, gxd4[u], gxb4v[u]), 0.f));
        float b = fmaf(dx, fxl[u] - fxm[u], fxm[u]);
        float xv = fmaf(m, fx[u] - b, b);
        xh[u] = (__bf16)xv;
        mh[u] = (__bf16)m;
        dh[u] = (__bf16)d;
      }
      *(bf16x4*)&pool[XA(parn, amt, akt) + salane * 8 + aj] = xh;
      *(bf16x4*)&pool[MAPL(parn, amt, akt) + salane * 8 + aj] = mh;
      *(bf16x4*)&pool[DAH(amt, akt) + salane * 8 + aj] = dh;
      // prefetch t+2 (stays in flight across the lgkm-only barriers)
      const long to = (long)(t + 2 < TT ? t + 2 : TT - 1) * II;
      fx  = *(const f32x4*)(Xp + to);
      fxl = *(const f32x4*)(XLp + to);
      fxm = *(const f32x4*)(XM + to + ai0);
      fm  = __builtin_nontemporal_load((const f32x4*)(MKp + to));
      fd  = __builtin_nontemporal_load((const f32x4*)(DEp + to));
    }

    // z,r: finish with h-part; r-sigmoid + rh-store (critical); z deferred to D
#pragma unroll
    for (int mt = 0; mt < 2; ++mt) {
      f32x4 az = azp[mt], ar = arp[mt];
#pragma unroll
      for (int kt = 2; kt < 6; ++kt) {
        bf16x8 ah = *(const bf16x8*)&pool[HAH(mt, kt - 2) + sl * 8];
        az = mfma16(ah, wzR[kt], az);
        ar = mfma16(ah, wrR[kt], ar);
      }
      azs[mt] = az;                          // z pre-act; sigmoid in D
      // h_tilde x/m partial (off critical path)
      f32x4 ahh = hb4;
#pragma unroll
      for (int kt = 0; kt < 2; ++kt) {
        bf16x8 ah = *(const bf16x8*)&pool[XA(par, mt, kt) + sl * 8];
        ahh = mfma16(ah, whR[kt], ahh);
      }
#pragma unroll
      for (int kt = 6; kt < 8; ++kt) {
        bf16x8 ah = *(const bf16x8*)&pool[MAPL(par, mt, kt - 6) + sl * 8];
        ahh = mfma16(ah, whR[kt], ahh);
      }
      ahp[mt] = ahh;
#pragma unroll
      for (int r = 0; r < 4; ++r) {
        float rv = sig2_(ar[r]);
        float rh = rv * h[mt][r];
        pool[RHH(mt, hq) + hsrow[r] * 8 + hj] = (__bf16)rh;
      }
    }
    barrier_lgkm();  // bar1 (LDS-only wait; vmem prefetch stays in flight)

    // ================= D-region =================
#pragma unroll
    for (int mt = 0; mt < 2; ++mt) {
      // finish h_tilde with rh-part (critical)
      f32x4 ahh = ahp[mt];
#pragma unroll
      for (int kt = 2; kt < 6; ++kt) {
        bf16x8 ah = *(const bf16x8*)&pool[RHH(mt, kt - 2) + sl * 8];
        ahh = mfma16(ah, whR[kt], ahh);
      }
      // z-sigmoid (deferred from C; hides under MFMAs)
      float zv[4];
#pragma unroll
      for (int r = 0; r < 4; ++r) zv[r] = sig2_(azs[mt][r]);
      // delta_h(t+1) + next-step z,r x/m partials (off critical path)
      f32x4 ad = gb4;
      if (more) {
#pragma unroll
        for (int kt = 0; kt < 2; ++kt) {
          bf16x8 ah = *(const bf16x8*)&pool[DAH(mt, kt) + sl * 8];
          ad = mfma16(ah, wgR[kt], ad);
        }
        f32x4 az = zb4, ar = rb4;
#pragma unroll
        for (int kt = 0; kt < 2; ++kt) {
          bf16x8 ah = *(const bf16x8*)&pool[XA(parn, mt, kt) + sl * 8];
          az = mfma16(ah, wzR[kt], az);
          ar = mfma16(ah, wrR[kt], ar);
        }
#pragma unroll
        for (int kt = 6; kt < 8; ++kt) {
          bf16x8 ah = *(const bf16x8*)&pool[MAPL(parn, mt, kt - 6) + sl * 8];
          az = mfma16(ah, wzR[kt], az);
          ar = mfma16(ah, wrR[kt], ar);
        }
        azp[mt] = az; arp[mt] = ar;
      }
#pragma unroll
      for (int r = 0; r < 4; ++r) {
        float ht = tanh2_(ahh[r]);
        float hn = fmaf(zv[r], ht - h[mt][r], h[mt][r]);
        if (more) {
          hn *= exp2_(-fmaxf(ad[r], 0.f));         // decay for step t+1
          pool[HAH(mt, hq) + hsrow[r] * 8 + hj] = (__bf16)hn;
        }
        h[mt][r] = hn;
      }
    }
    barrier_lgkm();  // bar2
  }

  // ---- fc epilogue (overlays pool) ----
  __syncthreads();
  float* hst = (float*)pool;                 // [32][132]
#pragma unroll
  for (int mt = 0; mt < 2; ++mt)
#pragma unroll
    for (int r = 0; r < 4; ++r) hst[(mt * 16 + lg * 4 + r) * 132 + cw] = h[mt][r];
  __syncthreads();
  if (tid < BB) {
    float acc = p[pn + OFF_FCB];
    for (int j = 0; j < HH; ++j) acc = fmaf(hst[tid * 132 + j], p[pn + OFF_FCW + j], acc);
    out[n * BATCH + b0 + tid] = rcpf_(1.f + exp2_(-acc * LOG2E));
  }
}

extern "C" void kernel_launch(void* const* d_in, const int* in_sizes, int n_in,
                              void* d_out, int out_size, void* d_ws, size_t ws_size,
                              hipStream_t stream) {
  const float* p  = (const float*)d_in[0];
  const float* X  = (const float*)d_in[1];
  const float* XL = (const float*)d_in[2];
  const float* XM = (const float*)d_in[3];
  const float* MK = (const float*)d_in[4];
  const float* DE = (const float*)d_in[5];
  float* out = (float*)d_out;
  __bf16* ws = (__bf16*)d_ws;
  if (ws_size < (size_t)WS_ELEMS * 2) return;

  hipLaunchKernelGGL(repack_kernel, dim3(4096), dim3(256), 0, stream, p, ws);
  hipLaunchKernelGGL(grud_main, dim3(NF * (BATCH / BB)), dim3(NTHR), 0, stream,
                     p, X, XL, XM, MK, DE, ws, out);
}

// Round 17
// 225.492 us; speedup vs baseline: 1.0145x; 1.0145x over previous
//
#include <hip/hip_runtime.h>

// GRU-D: nf=64, B=128, T=100, I=64, H=128, C=256.
// R17 = R16 with issue-order surgery: critical MFMAs first in each region,
//       VALU bursts moved into the matrix-pipe shadow. No other changes.
#define NF 64
#define BATCH 128
#define TT 100
#define II 64
#define HH 128
#define CC 256
#define BB 32
#define NTHR 512
#define PSTRIDE 111297

#define OFF_ZW 0
#define OFF_ZB 32768
#define OFF_RW 32896
#define OFF_RB 65664
#define OFF_HW 65792
#define OFF_HB 98560
#define OFF_GXW 98688
#define OFF_GXB 102784
#define OFF_GHW 102848
#define OFF_GHB 111040
#define OFF_FCW 111168
#define OFF_FCB 111296

#define LOG2E 1.4426950408889634f

// ws layout (bf16 elems), per-lane MFMA B-fragment order (hi only, pre-scaled)
#define ZR_PER_N 65536
#define H_BASE   (64 * ZR_PER_N)
#define H_PER_N  32768
#define G_BASE   (H_BASE + 64 * H_PER_N)
#define G_PER_N  8192
#define WS_ELEMS (G_BASE + 64 * G_PER_N)   // 6815744 bf16 = 13 MB

typedef __bf16 bf16x8 __attribute__((ext_vector_type(8)));
typedef __bf16 bf16x4 __attribute__((ext_vector_type(4)));
typedef float f32x4 __attribute__((ext_vector_type(4)));

__device__ __forceinline__ f32x4 mfma16(bf16x8 a, bf16x8 b, f32x4 c) {
  return __builtin_amdgcn_mfma_f32_16x16x32_bf16(a, b, c, 0, 0, 0);
}
__device__ __forceinline__ float rcpf_(float x) { return __builtin_amdgcn_rcpf(x); }
__device__ __forceinline__ float exp2_(float x) { return __builtin_amdgcn_exp2f(x); }
// inputs already scaled by log2e:
__device__ __forceinline__ float sig2_(float x) { return rcpf_(1.f + exp2_(-x)); }
// input already scaled by 2*log2e:
__device__ __forceinline__ float tanh2_(float x) {
  return fmaf(2.f, rcpf_(1.f + exp2_(-x)), -1.f);
}
// barrier that waits ONLY on LDS ops (keeps global prefetch in flight)
__device__ __forceinline__ void barrier_lgkm() {
  asm volatile("s_waitcnt lgkmcnt(0)\n\ts_barrier" ::: "memory");
}
// row swizzle within a [64][8] plane: physical row = r ^ 2*((r>>4)&3)
__device__ __forceinline__ int SW(int x) { return x ^ (((x >> 4) & 3) << 1); }

// LDS pool element-offsets (plane = [64 rows][8 j] = 512 elems):
#define XA(par, mt, kt)  ((((par)*2 + (mt)) * 2 + (kt)) * 512)
#define MAPL(par, mt, kt) (4096 + XA(par, mt, kt))
#define DAH(mt, kt) (8192 + (((mt)*2 + (kt)) * 512))
#define HAH(mt, q) (10240 + (((mt)*4 + (q)) * 512))
#define RHH(mt, q) (14336 + (((mt)*4 + (q)) * 512))
#define POOL_ELEMS 18432

// ---- repack: params -> B-fragment-ordered bf16 (hi only, log2e-scaled) ----
__global__ void repack_kernel(const float* __restrict__ p, __bf16* __restrict__ ws) {
  const int total = 4194304 + 2097152 + 524288;
  for (int e = blockIdx.x * 256 + threadIdx.x; e < total; e += gridDim.x * 256) {
    float wv; int dst;
    if (e < 4194304) {  // ZR  (scale log2e)
      int j = e & 7, l = (e >> 3) & 63, nt = (e >> 9) & 15, kt = (e >> 13) & 7, n = e >> 16;
      int c = kt * 32 + (l >> 4) * 8 + j, l15 = l & 15;
      long pn = (long)n * PSTRIDE;
      wv = (nt < 8) ? p[pn + OFF_ZW + (nt * 16 + l15) * CC + c]
                    : p[pn + OFF_RW + ((nt - 8) * 16 + l15) * CC + c];
      wv *= LOG2E;
      dst = n * ZR_PER_N + (kt * 16 + nt) * 512 + l * 8 + j;
    } else if (e < 4194304 + 2097152) {  // H  (scale 2*log2e for tanh form)
      int e2 = e - 4194304;
      int j = e2 & 7, l = (e2 >> 3) & 63, nt = (e2 >> 9) & 7, kt = (e2 >> 12) & 7, n = e2 >> 15;
      int c = kt * 32 + (l >> 4) * 8 + j, l15 = l & 15;
      wv = p[(long)n * PSTRIDE + OFF_HW + (nt * 16 + l15) * CC + c] * (2.f * LOG2E);
      dst = H_BASE + n * H_PER_N + (kt * 8 + nt) * 512 + l * 8 + j;
    } else {  // G  (scale log2e)
      int e2 = e - (4194304 + 2097152);
      int j = e2 & 7, l = (e2 >> 3) & 63, nt = (e2 >> 9) & 7, kt = (e2 >> 12) & 1, n = e2 >> 13;
      int c = kt * 32 + (l >> 4) * 8 + j, l15 = l & 15;
      wv = p[(long)n * PSTRIDE + OFF_GHW + (nt * 16 + l15) * II + c] * LOG2E;
      dst = G_BASE + n * G_PER_N + (kt * 8 + nt) * 512 + l * 8 + j;
    }
    ws[dst] = (__bf16)wv;
  }
}

// One block per (n, 32-batch chunk); 8 waves; 1 block/CU.
__global__ __launch_bounds__(NTHR, 2) void grud_main(
    const float* __restrict__ p, const float* __restrict__ X,
    const float* __restrict__ XL, const float* __restrict__ XM,
    const float* __restrict__ MK, const float* __restrict__ DE,
    const __bf16* __restrict__ ws, float* __restrict__ out) {
  __shared__ __align__(16) __bf16 pool[POOL_ELEMS];

  const int tid = threadIdx.x;
  const int w = tid >> 6, l = tid & 63;
  const int l15 = l & 15, lg = l >> 4;
  const int n = blockIdx.x & 63;            // same-n blocks -> same XCD
  const int b0 = (blockIdx.x >> 6) * BB;
  const long pn = (long)n * PSTRIDE;
  const int cw = w * 16 + l15;
  const int sl = SW(l);

  // ---- all weight fragments in registers (loaded once, 104 VGPR) ----
  bf16x8 wgR[2], wzR[8], wrR[8], whR[8];
  {
    const __bf16* wzr = ws + n * ZR_PER_N;
    const __bf16* wh_ = ws + H_BASE + n * H_PER_N;
    const __bf16* wg_ = ws + G_BASE + n * G_PER_N;
#pragma unroll
    for (int kt = 0; kt < 2; ++kt)
      wgR[kt] = *(const bf16x8*)(wg_ + (kt * 8 + w) * 512 + l * 8);
#pragma unroll
    for (int kt = 0; kt < 8; ++kt) {
      wzR[kt] = *(const bf16x8*)(wzr + (kt * 16 + w) * 512 + l * 8);
      wrR[kt] = *(const bf16x8*)(wzr + (kt * 16 + 8 + w) * 512 + l * 8);
      whR[kt] = *(const bf16x8*)(wh_ + (kt * 8 + w) * 512 + l * 8);
    }
  }

  const float zb = p[pn + OFF_ZB + cw] * LOG2E;
  const float rb = p[pn + OFF_RB + cw] * LOG2E;
  const float hb = p[pn + OFF_HB + cw] * (2.f * LOG2E);
  const float gb = p[pn + OFF_GHB + cw] * LOG2E;
  const f32x4 zb4 = {zb, zb, zb, zb};
  const f32x4 rb4 = {rb, rb, rb, rb};
  const f32x4 hb4 = {hb, hb, hb, hb};
  const f32x4 gb4 = {gb, gb, gb, gb};

  // this lane's h-column coords (global k = 64 + cw)
  const int hq = ((64 + cw) >> 5) - 2;                 // plane q 0..3
  const int qh = (cw >> 3) & 3;
  const int hj = cw & 7;
  int hsrow[4];
#pragma unroll
  for (int r = 0; r < 4; ++r) hsrow[r] = qh * 16 + ((lg * 4 + r) ^ (qh << 1));

  // phase-A mapping: thread -> (batch row 0..31, 4-wide i block)
  const int arow = tid >> 4;
  const int ai0 = (tid & 15) * 4;
  const int amt = arow >> 4;
  const int akt = ai0 >> 5;
  const int salane = SW(((ai0 >> 3) & 3) * 16 + (arow & 15));
  const int aj = ai0 & 7;
  const float* __restrict__ Xp  = X  + (long)(b0 + arow) * TT * II + ai0;
  const float* __restrict__ XLp = XL + (long)(b0 + arow) * TT * II + ai0;
  const float* __restrict__ MKp = MK + ((long)(n * BATCH + b0 + arow) * TT) * II + ai0;
  const float* __restrict__ DEp = DE + ((long)(n * BATCH + b0 + arow) * TT) * II + ai0;
  float gxd4[4], gxb4v[4];
#pragma unroll
  for (int u = 0; u < 4; ++u) {
    gxd4[u] = p[pn + OFF_GXW + (ai0 + u) * 65] * LOG2E;
    gxb4v[u] = p[pn + OFF_GXB + ai0 + u] * LOG2E;
  }

  float h[2][4] = {{0.f, 0.f, 0.f, 0.f}, {0.f, 0.f, 0.f, 0.f}};
  f32x4 azp[2], arp[2];   // z,r partial accumulators (x/m part of step t)
  f32x4 ahp[2];           // h_tilde partial accumulator (x/m part of step t)
  f32x4 azs[2];           // completed z pre-activations, consumed in D

  // ---- prologue: zero hA planes; A(0); prefetch(1) ----
  for (int e = tid; e < 4096; e += NTHR) pool[10240 + e] = (__bf16)0.f;

  f32x4 fx  = *(const f32x4*)Xp;
  f32x4 fxl = *(const f32x4*)XLp;
  f32x4 fxm = *(const f32x4*)(XM + ai0);
  f32x4 fm  = __builtin_nontemporal_load((const f32x4*)MKp);
  f32x4 fd  = __builtin_nontemporal_load((const f32x4*)DEp);
  {
    bf16x4 xh, mh;
#pragma unroll
    for (int u = 0; u < 4; ++u) {
      float m = fm[u], d = fd[u];
      float dx = exp2_(-fmaxf(fmaf(d, gxd4[u], gxb4v[u]), 0.f));
      float b = fmaf(dx, fxl[u] - fxm[u], fxm[u]);
      float xv = fmaf(m, fx[u] - b, b);
      xh[u] = (__bf16)xv;
      mh[u] = (__bf16)m;
    }
    *(bf16x4*)&pool[XA(0, amt, akt) + salane * 8 + aj] = xh;
    *(bf16x4*)&pool[MAPL(0, amt, akt) + salane * 8 + aj] = mh;
  }
  {
    const long to = (long)(TT > 1 ? 1 : 0) * II;
    fx  = *(const f32x4*)(Xp + to);
    fxl = *(const f32x4*)(XLp + to);
    fxm = *(const f32x4*)(XM + to + ai0);
    fm  = __builtin_nontemporal_load((const f32x4*)(MKp + to));
    fd  = __builtin_nontemporal_load((const f32x4*)(DEp + to));
  }
  __syncthreads();

  // z,r x/m partials for t=0
#pragma unroll
  for (int mt = 0; mt < 2; ++mt) {
    f32x4 az = zb4, ar = rb4;
#pragma unroll
    for (int kt = 0; kt < 2; ++kt) {
      bf16x8 ah = *(const bf16x8*)&pool[XA(0, mt, kt) + sl * 8];
      az = mfma16(ah, wzR[kt], az);
      ar = mfma16(ah, wrR[kt], ar);
    }
#pragma unroll
    for (int kt = 6; kt < 8; ++kt) {
      bf16x8 ah = *(const bf16x8*)&pool[MAPL(0, mt, kt - 6) + sl * 8];
      az = mfma16(ah, wzR[kt], az);
      ar = mfma16(ah, wrR[kt], ar);
    }
    azp[mt] = az; arp[mt] = ar;
  }

  for (int t = 0; t < TT; ++t) {
    const int par = t & 1, parn = par ^ 1;
    const bool more = (t + 1 < TT);

    // ================= C-region =================
    // (1) CRITICAL: finish z,r with h-part — issue these MFMAs first
    f32x4 azc[2], arc[2];
#pragma unroll
    for (int mt = 0; mt < 2; ++mt) {
      f32x4 az = azp[mt], ar = arp[mt];
#pragma unroll
      for (int kt = 2; kt < 6; ++kt) {
        bf16x8 ah = *(const bf16x8*)&pool[HAH(mt, kt - 2) + sl * 8];
        az = mfma16(ah, wzR[kt], az);
        ar = mfma16(ah, wrR[kt], ar);
      }
      azc[mt] = az; arc[mt] = ar;
    }

    // (2) A(t+1) elementwise VALU — fills the matrix-pipe shadow
    if (more) {
      bf16x4 xh, mh, dh;
#pragma unroll
      for (int u = 0; u < 4; ++u) {
        float m = fm[u], d = fd[u];
        float dx = exp2_(-fmaxf(fmaf(d, gxd4[u], gxb4v[u]), 0.f));
        float b = fmaf(dx, fxl[u] - fxm[u], fxm[u]);
        float xv = fmaf(m, fx[u] - b, b);
        xh[u] = (__bf16)xv;
        mh[u] = (__bf16)m;
        dh[u] = (__bf16)d;
      }
      *(bf16x4*)&pool[XA(parn, amt, akt) + salane * 8 + aj] = xh;
      *(bf16x4*)&pool[MAPL(parn, amt, akt) + salane * 8 + aj] = mh;
      *(bf16x4*)&pool[DAH(amt, akt) + salane * 8 + aj] = dh;
      // prefetch t+2 (stays in flight across the lgkm-only barriers)
      const long to = (long)(t + 2 < TT ? t + 2 : TT - 1) * II;
      fx  = *(const f32x4*)(Xp + to);
      fxl = *(const f32x4*)(XLp + to);
      fxm = *(const f32x4*)(XM + to + ai0);
      fm  = __builtin_nontemporal_load((const f32x4*)(MKp + to));
      fd  = __builtin_nontemporal_load((const f32x4*)(DEp + to));
    }

    // (3) h_tilde x/m partials — independent MFMAs cover ar latency
#pragma unroll
    for (int mt = 0; mt < 2; ++mt) {
      f32x4 ahh = hb4;
#pragma unroll
      for (int kt = 0; kt < 2; ++kt) {
        bf16x8 ah = *(const bf16x8*)&pool[XA(par, mt, kt) + sl * 8];
        ahh = mfma16(ah, whR[kt], ahh);
      }
#pragma unroll
      for (int kt = 6; kt < 8; ++kt) {
        bf16x8 ah = *(const bf16x8*)&pool[MAPL(par, mt, kt - 6) + sl * 8];
        ahh = mfma16(ah, whR[kt], ahh);
      }
      ahp[mt] = ahh;
    }

    // (4) r-sigmoid + rh store; z deferred to D
#pragma unroll
    for (int mt = 0; mt < 2; ++mt) {
      azs[mt] = azc[mt];
#pragma unroll
      for (int r = 0; r < 4; ++r) {
        float rv = sig2_(arc[mt][r]);
        float rh = rv * h[mt][r];
        pool[RHH(mt, hq) + hsrow[r] * 8 + hj] = (__bf16)rh;
      }
    }
    barrier_lgkm();  // bar1

    // ================= D-region =================
    // (1) CRITICAL: finish h_tilde with rh-part — first
    f32x4 ahc[2];
#pragma unroll
    for (int mt = 0; mt < 2; ++mt) {
      f32x4 ahh = ahp[mt];
#pragma unroll
      for (int kt = 2; kt < 6; ++kt) {
        bf16x8 ah = *(const bf16x8*)&pool[RHH(mt, kt - 2) + sl * 8];
        ahh = mfma16(ah, whR[kt], ahh);
      }
      ahc[mt] = ahh;
    }

    // (2) z-sigmoid in the MFMA shadow
    float zv[2][4];
#pragma unroll
    for (int mt = 0; mt < 2; ++mt)
#pragma unroll
      for (int r = 0; r < 4; ++r) zv[mt][r] = sig2_(azs[mt][r]);

    // (3) off-path MFMAs: delta_h(t+1) + next-step z,r x/m partials
    f32x4 adv[2];
    if (more) {
#pragma unroll
      for (int mt = 0; mt < 2; ++mt) {
        f32x4 ad = gb4;
#pragma unroll
        for (int kt = 0; kt < 2; ++kt) {
          bf16x8 ah = *(const bf16x8*)&pool[DAH(mt, kt) + sl * 8];
          ad = mfma16(ah, wgR[kt], ad);
        }
        adv[mt] = ad;
        f32x4 az = zb4, ar = rb4;
#pragma unroll
        for (int kt = 0; kt < 2; ++kt) {
          bf16x8 ah = *(const bf16x8*)&pool[XA(parn, mt, kt) + sl * 8];
          az = mfma16(ah, wzR[kt], az);
          ar = mfma16(ah, wrR[kt], ar);
        }
#pragma unroll
        for (int kt = 6; kt < 8; ++kt) {
          bf16x8 ah = *(const bf16x8*)&pool[MAPL(parn, mt, kt - 6) + sl * 8];
          az = mfma16(ah, wzR[kt], az);
          ar = mfma16(ah, wrR[kt], ar);
        }
        azp[mt] = az; arp[mt] = ar;
      }
    }

    // (4) h update + decay + hA store
#pragma unroll
    for (int mt = 0; mt < 2; ++mt) {
#pragma unroll
      for (int r = 0; r < 4; ++r) {
        float ht = tanh2_(ahc[mt][r]);
        float hn = fmaf(zv[mt][r], ht - h[mt][r], h[mt][r]);
        if (more) {
          hn *= exp2_(-fmaxf(adv[mt][r], 0.f));    // decay for step t+1
          pool[HAH(mt, hq) + hsrow[r] * 8 + hj] = (__bf16)hn;
        }
        h[mt][r] = hn;
      }
    }
    barrier_lgkm();  // bar2
  }

  // ---- fc epilogue (overlays pool) ----
  __syncthreads();
  float* hst = (float*)pool;                 // [32][132]
#pragma unroll
  for (int mt = 0; mt < 2; ++mt)
#pragma unroll
    for (int r = 0; r < 4; ++r) hst[(mt * 16 + lg * 4 + r) * 132 + cw] = h[mt][r];
  __syncthreads();
  if (tid < BB) {
    float acc = p[pn + OFF_FCB];
    for (int j = 0; j < HH; ++j) acc = fmaf(hst[tid * 132 + j], p[pn + OFF_FCW + j], acc);
    out[n * BATCH + b0 + tid] = rcpf_(1.f + exp2_(-acc * LOG2E));
  }
}

extern "C" void kernel_launch(void* const* d_in, const int* in_sizes, int n_in,
                              void* d_out, int out_size, void* d_ws, size_t ws_size,
                              hipStream_t stream) {
  const float* p  = (const float*)d_in[0];
  const float* X  = (const float*)d_in[1];
  const float* XL = (const float*)d_in[2];
  const float* XM = (const float*)d_in[3];
  const float* MK = (const float*)d_in[4];
  const float* DE = (const float*)d_in[5];
  float* out = (float*)d_out;
  __bf16* ws = (__bf16*)d_ws;
  if (ws_size < (size_t)WS_ELEMS * 2) return;

  hipLaunchKernelGGL(repack_kernel, dim3(4096), dim3(256), 0, stream, p, ws);
  hipLaunchKernelGGL(grud_main, dim3(NF * (BATCH / BB)), dim3(NTHR), 0, stream,
                     p, X, XL, XM, MK, DE, ws, out);
}